// Round 4
// baseline (1640.542 us; speedup 1.0000x reference)
//
#include <hip/hip_runtime.h>
#include <hip/hip_bf16.h>
#include <stdint.h>

static constexpr int N_NODES = 100000;
static constexpr int N_EDGES = 1600000;
static constexpr int PAD_ROWS = 100096;   // 782 * 128, removes GEMM A-tile bounds checks

// block-local partition CSR build: 512 rows per coarse bucket
static constexpr int CB_SHIFT = 9;
static constexpr int CRPB = 1 << CB_SHIFT;            // 512 rows / bucket
static constexpr int NCB = 196;                       // covers 100352 >= PAD_ROWS
static constexpr int CCAP = 8960;                     // mean 8192, sd 90 -> +8.5 sigma
static constexpr int CHUNK = 4096;                    // edges per partition block

typedef _Float16 f16;
using f16x8 = __attribute__((ext_vector_type(8))) _Float16;
using f16x4v = __attribute__((ext_vector_type(4))) _Float16;
using f32x4 = __attribute__((ext_vector_type(4))) float;

__device__ __forceinline__ void gld_lds16(const void* g, void* l) {
  __builtin_amdgcn_global_load_lds((const __attribute__((address_space(1))) void*)g,
                                   (__attribute__((address_space(3))) void*)l, 16, 0, 0);
}

// piecewise multi-term ReLU activation: 1.8*soft(0.1) - 0.8*soft(0.5)
__device__ __forceinline__ float custom_act(float x) {
  float s1 = fmaxf(x - 0.1f, 0.f) - fmaxf(-x - 0.1f, 0.f);
  float s2 = fmaxf(x - 0.5f, 0.f) - fmaxf(-x - 0.5f, 0.f);
  return 1.8f * s1 - 0.8f * s2;
}

// ---------------- conversions ----------------
__global__ __launch_bounds__(256) void xconv_k(const float* __restrict__ src, f16* __restrict__ dst, int n4) {
  int i = blockIdx.x * 256 + threadIdx.x;
  if (i < n4) {
    float4 v = ((const float4*)src)[i];
    f16x4v h = {(f16)v.x, (f16)v.y, (f16)v.z, (f16)v.w};
    ((f16x4v*)dst)[i] = h;
  }
}

// all 10 weight transposes (fp32 [K][N] -> f16 [N][K]) in one dispatch
struct WC {
  const float* src[10];
  f16* dst[10];
  int K[10], N[10], beg[11];
};
__global__ __launch_bounds__(256) void wconv_k(WC wc) {
  int i = blockIdx.x * 256 + threadIdx.x;
  if (i >= wc.beg[10]) return;
  int s = 0;
  while (s < 9 && i >= wc.beg[s + 1]) ++s;
  int local = i - wc.beg[s];
  int N = wc.N[s];
  int k = local / N, n = local - k * N;
  wc.dst[s][n * wc.K[s] + k] = (f16)wc.src[s][local];
}

// ---------------- block-local partition (phase 1) ----------------
__global__ __launch_bounds__(256) void part_k(const int* __restrict__ Ai, const float* __restrict__ Av,
                                              int* __restrict__ bcA, int2* __restrict__ bufA,
                                              const int* __restrict__ Li, const float* __restrict__ Lv,
                                              int* __restrict__ bcL, int2* __restrict__ bufL, int E) {
  __shared__ int histA[NCB], histL[NCB];
  __shared__ int baseA[NCB], baseL[NCB];
  int tid = threadIdx.x;
  int e0 = blockIdx.x * CHUNK;
  int e1 = min(e0 + CHUNK, E);
  for (int i = tid; i < NCB; i += 256) { histA[i] = 0; histL[i] = 0; }
  __syncthreads();
  for (int e = e0 + tid; e < e1; e += 256) {
    atomicAdd(&histA[Ai[e] >> CB_SHIFT], 1);
    atomicAdd(&histL[Li[e] >> CB_SHIFT], 1);
  }
  __syncthreads();
  if (tid < NCB) {
    int hA = histA[tid], hL = histL[tid];
    baseA[tid] = hA ? atomicAdd(&bcA[tid * 16], hA) : 0;
    baseL[tid] = hL ? atomicAdd(&bcL[tid * 16], hL) : 0;
    histA[tid] = 0;
    histL[tid] = 0;
  }
  __syncthreads();
  for (int e = e0 + tid; e < e1; e += 256) {
    {
      int r = Ai[e], c = Ai[E + e];
      int b = r >> CB_SHIFT;
      int p = baseA[b] + atomicAdd(&histA[b], 1);
      if (p < CCAP) bufA[(size_t)b * CCAP + p] = make_int2(((r & (CRPB - 1)) << 17) | c, __float_as_int(Av[e]));
    }
    {
      int r = Li[e], c = Li[E + e];
      int b = r >> CB_SHIFT;
      int p = baseL[b] + atomicAdd(&histL[b], 1);
      if (p < CCAP) bufL[(size_t)b * CCAP + p] = make_int2(((r & (CRPB - 1)) << 17) | c, __float_as_int(Lv[e]));
    }
  }
}

// scan bucket totals (strided counters) -> bucket base offsets
__global__ __launch_bounds__(1024) void scan_k(const int* __restrict__ cntA, int* __restrict__ rpA,
                                               const int* __restrict__ cntL, int* __restrict__ rpL,
                                               int n, int stride) {
  const int* cnt = blockIdx.x ? cntL : cntA;
  int* rp = blockIdx.x ? rpL : rpA;
  __shared__ int wsum[16];
  __shared__ int carry_s;
  int tid = threadIdx.x, lane = tid & 63, wv = tid >> 6;
  if (tid == 0) carry_s = 0;
  __syncthreads();
  for (int base = 0; base < n; base += 1024) {
    int i = base + tid;
    int v = (i < n) ? cnt[i * stride] : 0;
    int s = v;
    #pragma unroll
    for (int off = 1; off < 64; off <<= 1) {
      int t = __shfl_up(s, off, 64);
      if (lane >= off) s += t;
    }
    if (lane == 63) wsum[wv] = s;
    __syncthreads();
    if (wv == 0 && lane < 16) {
      int w = wsum[lane];
      #pragma unroll
      for (int off = 1; off < 16; off <<= 1) {
        int t = __shfl_up(w, off, 64);
        if (lane >= off) w += t;
      }
      wsum[lane] = w;
    }
    __syncthreads();
    int carry = carry_s;
    int woff = wv ? wsum[wv - 1] : 0;
    if (i < n) rp[i] = carry + woff + s - v;
    __syncthreads();
    if (tid == 1023) carry_s = carry + woff + s;
    __syncthreads();
  }
  if (tid == 0) rp[n] = carry_s;
}

// ---------------- per-bucket ordering (phase 2) ----------------
__global__ __launch_bounds__(256) void place_k(const int* __restrict__ bcA, const int* __restrict__ bbA,
                                               const int2* __restrict__ bufA, int* __restrict__ rpA,
                                               int2* __restrict__ recA,
                                               const int* __restrict__ bcL, const int* __restrict__ bbL,
                                               const int2* __restrict__ bufL, int* __restrict__ rpL,
                                               int2* __restrict__ recL) {
  const int b = blockIdx.x;
  const int* bc; const int* bb; const int2* buf; int* rp; int2* rec;
  if (blockIdx.y) { bc = bcL; bb = bbL; buf = bufL; rp = rpL; rec = recL; }
  else            { bc = bcA; bb = bbA; buf = bufA; rp = rpA; rec = recA; }
  __shared__ int lcnt[CRPB];
  __shared__ int wsum[4];
  int tid = threadIdx.x, lane = tid & 63, wv = tid >> 6;
  int nrec = min(bc[b * 16], CCAP);
  const int2* src = buf + (size_t)b * CCAP;
  lcnt[2 * tid] = 0;
  lcnt[2 * tid + 1] = 0;
  __syncthreads();
  for (int i = tid; i < nrec; i += 256) atomicAdd(&lcnt[src[i].x >> 17], 1);
  __syncthreads();
  int c0 = lcnt[2 * tid], c1 = lcnt[2 * tid + 1];
  int s = c0 + c1;
  int incl = s;
  #pragma unroll
  for (int off = 1; off < 64; off <<= 1) {
    int t = __shfl_up(incl, off, 64);
    if (lane >= off) incl += t;
  }
  if (lane == 63) wsum[wv] = incl;
  __syncthreads();
  int woff = 0;
  for (int w = 0; w < wv; ++w) woff += wsum[w];
  int base0 = bb[b] + woff + incl - s;    // exclusive prefix + global bucket base
  int base1 = base0 + c0;
  __syncthreads();
  lcnt[2 * tid] = base0;
  lcnt[2 * tid + 1] = base1;
  rp[b * CRPB + 2 * tid] = base0;
  rp[b * CRPB + 2 * tid + 1] = base1;
  __syncthreads();
  for (int i = tid; i < nrec; i += 256) {
    int2 r = src[i];
    int pos = atomicAdd(&lcnt[r.x >> 17], 1);
    rec[pos] = make_int2(r.x & 0x1FFFF, r.y);
  }
}

// ---------------- gather SpMM (unchanged from round 3) ----------------
template<int VEC>
__global__ __launch_bounds__(256) void spmm_k(const int* __restrict__ rp, const int2* __restrict__ rec,
                                              const f16* __restrict__ X,
                                              const f16* __restrict__ base, const float* __restrict__ bias,
                                              f16* __restrict__ out, int mode, int nrows) {
  int lane = threadIdx.x & 63;
  int row = blockIdx.x * 4 + (threadIdx.x >> 6);
  if (row >= nrows) return;
  const int M = VEC * 64;
  int p0 = __builtin_amdgcn_readfirstlane(rp[row]);
  int p1 = __builtin_amdgcn_readfirstlane(rp[row + 1]);
  float acc[VEC] = {};
  int p = p0;
  for (; p + 7 < p1; p += 8) {
    int2 e[8];
    #pragma unroll
    for (int u = 0; u < 8; ++u) e[u] = rec[p + u];
    if (VEC == 4) {
      f16x4v xv[8];
      #pragma unroll
      for (int u = 0; u < 8; ++u) xv[u] = *(const f16x4v*)(X + (size_t)e[u].x * M + lane * 4);
      #pragma unroll
      for (int u = 0; u < 8; ++u) {
        float v = __int_as_float(e[u].y);
        #pragma unroll
        for (int j = 0; j < 4; ++j) acc[j] += v * (float)xv[u][j];
      }
    } else {
      float xv[8];
      #pragma unroll
      for (int u = 0; u < 8; ++u) xv[u] = (float)X[(size_t)e[u].x * M + lane];
      #pragma unroll
      for (int u = 0; u < 8; ++u) acc[0] += __int_as_float(e[u].y) * xv[u];
    }
  }
  for (; p + 1 < p1; p += 2) {
    int2 e0 = rec[p], e1 = rec[p + 1];
    float v0 = __int_as_float(e0.y), v1 = __int_as_float(e1.y);
    if (VEC == 4) {
      f16x4v x0 = *(const f16x4v*)(X + (size_t)e0.x * M + lane * 4);
      f16x4v x1 = *(const f16x4v*)(X + (size_t)e1.x * M + lane * 4);
      #pragma unroll
      for (int j = 0; j < 4; ++j) acc[j] += v0 * (float)x0[j] + v1 * (float)x1[j];
    } else {
      float x0 = (float)X[(size_t)e0.x * M + lane];
      float x1 = (float)X[(size_t)e1.x * M + lane];
      acc[0] += v0 * x0 + v1 * x1;
    }
  }
  if (p < p1) {
    int2 e0 = rec[p];
    float v0 = __int_as_float(e0.y);
    if (VEC == 4) {
      f16x4v x0 = *(const f16x4v*)(X + (size_t)e0.x * M + lane * 4);
      #pragma unroll
      for (int j = 0; j < 4; ++j) acc[j] += v0 * (float)x0[j];
    } else {
      acc[0] += v0 * (float)X[(size_t)e0.x * M + lane];
    }
  }
  size_t o = (size_t)row * M + (size_t)lane * VEC;
  if (VEC == 4) {
    f16x4v r;
    if (mode == 0) {
      #pragma unroll
      for (int j = 0; j < 4; ++j) r[j] = (f16)fmaxf(acc[j] + bias[lane * 4 + j], 0.f);
    } else {
      f16x4v bv = *(const f16x4v*)(base + o);
      #pragma unroll
      for (int j = 0; j < 4; ++j) r[j] = (f16)custom_act((float)bv[j] - acc[j]);
    }
    *(f16x4v*)(out + o) = r;
  } else {
    if (mode == 0) out[o] = (f16)fmaxf(acc[0] + bias[lane], 0.f);
    else out[o] = (f16)custom_act((float)base[o] - acc[0]);
  }
}

// ---------------- multi-job f16 MFMA GEMM, BK=64, XOR-swizzled LDS ----------------
// Per blockIdx.y job: C = epi(A1@B1 [+ A2@B2] + bias), tile 128 x bn (bn in {64,128}).
// LDS layout: As[row][64] with 16B granule g of row r stored at slot g^(r&7)
// (applied via pre-swizzled global source; gld_lds dest stays linear) -> ds_read_b128
// fragment reads are 2-way-bank (free) instead of 8-way at 64B row stride.
struct GJobs {
  const f16* A1[3]; const f16* A2[3];
  const f16* B1[3]; const f16* B2[3];
  const float* bias[3];
  void* C[3];
  int K1[3], K2[3], cf16[3], epi[3], ldc[3], bn[3], c0[3];
};

__global__ __launch_bounds__(256) void gemm_k(GJobs jb, int nrows) {
  __shared__ f16 As[128 * 64];
  __shared__ f16 Bs[128 * 64];
  const int j = blockIdx.y;
  const int BN = jb.bn[j], c0 = jb.c0[j], ldc = jb.ldc[j];
  const int nbt = BN >> 4;
  int tid = threadIdx.x, lane = tid & 63, wv = tid >> 6;
  int m16 = lane & 15, quad = lane >> 4;
  int r0 = blockIdx.x * 128;
  int wr0 = wv * 32;
  f32x4 acc[2][8] = {};
  // staging: lane l -> row (l>>3), granule slot (l&7); global granule = slot ^ (row&7)
  int srow = lane >> 3;
  int sg = (lane & 7) ^ (srow & 7);
  int bRows = (BN == 128) ? 32 : 16;
  int aswz = (m16 & 7) * 8;   // f16 offset of XOR term for fragment reads
  for (int src = 0; src < 2; ++src) {
    const f16* A = src ? jb.A2[j] : jb.A1[j];
    if (!A) continue;
    int K = src ? jb.K2[j] : jb.K1[j];
    const f16* Bt = src ? jb.B2[j] : jb.B1[j];
    const f16* gA = A + (size_t)(r0 + wr0 + srow) * K + sg * 8;
    const f16* gB = Bt + (size_t)(c0 + wv * bRows + srow) * K + sg * 8;
    f16* lA = &As[wr0 * 64];
    f16* lB = &Bs[wv * bRows * 64];
    for (int k0 = 0; k0 < K; k0 += 64) {
      #pragma unroll
      for (int c = 0; c < 4; ++c) gld_lds16(gA + k0 + (size_t)(c * 8) * K, lA + c * 512);
      gld_lds16(gB + k0, lB);
      gld_lds16(gB + k0 + (size_t)8 * K, lB + 512);
      if (BN == 128) {
        gld_lds16(gB + k0 + (size_t)16 * K, lB + 1024);
        gld_lds16(gB + k0 + (size_t)24 * K, lB + 1536);
      }
      __syncthreads();
      #pragma unroll
      for (int ks = 0; ks < 2; ++ks) {
        int gsl = ((ks * 4 + quad) * 8) ^ aswz;
        f16x8 a0 = *(const f16x8*)&As[(wr0 + m16) * 64 + gsl];
        f16x8 a1 = *(const f16x8*)&As[(wr0 + 16 + m16) * 64 + gsl];
        if (BN == 128) {
          #pragma unroll
          for (int bt = 0; bt < 8; ++bt) {
            f16x8 b = *(const f16x8*)&Bs[(bt * 16 + m16) * 64 + gsl];
            acc[0][bt] = __builtin_amdgcn_mfma_f32_16x16x32_f16(a0, b, acc[0][bt], 0, 0, 0);
            acc[1][bt] = __builtin_amdgcn_mfma_f32_16x16x32_f16(a1, b, acc[1][bt], 0, 0, 0);
          }
        } else {
          #pragma unroll
          for (int bt = 0; bt < 4; ++bt) {
            f16x8 b = *(const f16x8*)&Bs[(bt * 16 + m16) * 64 + gsl];
            acc[0][bt] = __builtin_amdgcn_mfma_f32_16x16x32_f16(a0, b, acc[0][bt], 0, 0, 0);
            acc[1][bt] = __builtin_amdgcn_mfma_f32_16x16x32_f16(a1, b, acc[1][bt], 0, 0, 0);
          }
        }
      }
      __syncthreads();
    }
  }
  const float* bias = jb.bias[j];
  int cf16 = jb.cf16[j], epi = jb.epi[j];
  void* C = jb.C[j];
  for (int rt = 0; rt < 2; ++rt) {
    for (int bt = 0; bt < nbt; ++bt) {
      #pragma unroll
      for (int jj = 0; jj < 4; ++jj) {
        int row = r0 + wr0 + rt * 16 + quad * 4 + jj;
        if (row >= nrows) continue;
        int colp = c0 + bt * 16 + m16;
        float v = acc[rt][bt][jj];
        if (bias) v += bias[colp];
        if (epi == 1) v = tanhf(v);
        size_t o = (size_t)row * ldc + colp;
        if (cf16) ((f16*)C)[o] = (f16)v;
        else ((float*)C)[o] = v;
      }
    }
  }
}

extern "C" void kernel_launch(void* const* d_in, const int* in_sizes, int n_in,
                              void* d_out, int out_size, void* d_ws, size_t ws_size,
                              hipStream_t stream) {
  const float* x  = (const float*)d_in[0];
  const int*   Ai = (const int*)d_in[1];
  const float* Av = (const float*)d_in[2];
  const int*   Li = (const int*)d_in[3];
  const float* Lv = (const float*)d_in[4];
  const float* gcn_w0 = (const float*)d_in[5];
  const float* gcn_b0 = (const float*)d_in[6];
  const float* pai1_0 = (const float*)d_in[7];
  const float* pai2_0 = (const float*)d_in[8];
  const float* w1_w0  = (const float*)d_in[9];
  const float* w1_b0  = (const float*)d_in[10];
  const float* w2_w0  = (const float*)d_in[11];
  const float* w2_b0  = (const float*)d_in[12];
  const float* gcn_w1 = (const float*)d_in[13];
  const float* gcn_b1 = (const float*)d_in[14];
  const float* pai1_1 = (const float*)d_in[15];
  const float* pai2_1 = (const float*)d_in[16];
  const float* w1_w1  = (const float*)d_in[17];
  const float* w1_b1  = (const float*)d_in[18];
  const float* w2_w1  = (const float*)d_in[19];
  const float* w2_b1  = (const float*)d_in[20];
  float* out = (float*)d_out;

  const int N = N_NODES, E = N_EDGES;
  const size_t PH = (size_t)PAD_ROWS * 256;
  const size_t Pd = (size_t)PAD_ROWS * 64;
  const size_t Nd = (size_t)N * 64;

  // ---- workspace carve ----
  f16* xh  = (f16*)d_ws;               // PH
  f16* R1  = xh + PH;                  // PH
  f16* R2  = R1 + PH;                  // PH
  f16* wts = R2 + PH;                  // 274432 f16 weight pool
  f16* gcn_w0t = wts;
  f16* pai1_0t = gcn_w0t + 65536;
  f16* pai2_0t = pai1_0t + 65536;
  f16* w1_w0t  = pai2_0t + 65536;
  f16* w2_w0t  = w1_w0t + 16384;
  f16* gcn_w1t = w2_w0t + 16384;
  f16* pai2_1t = gcn_w1t + 16384;
  f16* pai1_1t = pai2_1t + 16384;
  f16* w1_w1t  = pai1_1t + 4096;
  f16* w2_w1t  = w1_w1t + 4096;
  int2* recA = (int2*)(((uintptr_t)(w2_w1t + 4096) + 255) & ~(uintptr_t)255);  // E
  int2* recL = recA + E;                                                        // E
  int*  rpA  = (int*)(recL + E);       // PAD_ROWS + 512
  int*  rpL  = rpA + (PAD_ROWS + 512);
  int*  bcA  = rpL + (PAD_ROWS + 512); // NCB*16
  int*  bcL  = bcA + NCB * 16;
  int*  bbA  = bcL + NCB * 16;         // NCB+1
  int*  bbL  = bbA + (NCB + 1);        // NCB+1

  int2* bufA = (int2*)R1;                       // aliases R1 (stream-ordered)
  int2* bufL = bufA + (size_t)NCB * CCAP;

  // layer-1 sub-buffers inside R2 (ldc=64, padded rows)
  f16* T1h   = R2;
  f16* Ztp1h = R2 + Pd;
  f16* Z1bh  = R2 + 2 * Pd;

  // ---- conversions ----
  xconv_k<<<(int)(((size_t)N * 64 + 255) / 256), 256, 0, stream>>>(x, xh, N * 64);
  {
    WC wc;
    const float* s[10] = {gcn_w0, pai1_0, pai2_0, w1_w0, w2_w0, gcn_w1, pai2_1, pai1_1, w1_w1, w2_w1};
    f16* d[10] = {gcn_w0t, pai1_0t, pai2_0t, w1_w0t, w2_w0t, gcn_w1t, pai2_1t, pai1_1t, w1_w1t, w2_w1t};
    int K[10] = {256, 256, 256, 256, 256, 256, 256, 64, 64, 64};
    int Nn[10] = {256, 256, 256, 64, 64, 64, 64, 64, 64, 64};
    int off = 0;
    for (int i = 0; i < 10; ++i) {
      wc.src[i] = s[i]; wc.dst[i] = d[i]; wc.K[i] = K[i]; wc.N[i] = Nn[i];
      wc.beg[i] = off; off += K[i] * Nn[i];
    }
    wc.beg[10] = off;
    wconv_k<<<(off + 255) / 256, 256, 0, stream>>>(wc);
  }

  // ---- CSR build ----
  hipMemsetAsync(bcA, 0, sizeof(int) * (size_t)NCB * 16 * 2, stream);
  part_k<<<(E + CHUNK - 1) / CHUNK, 256, 0, stream>>>(Ai, Av, bcA, bufA, Li, Lv, bcL, bufL, E);
  scan_k<<<2, 1024, 0, stream>>>(bcA, bbA, bcL, bbL, NCB, 16);
  place_k<<<dim3(NCB, 2), 256, 0, stream>>>(bcA, bbA, bufA, rpA, recA,
                                            bcL, bbL, bufL, rpL, recL);

  const int MB = PAD_ROWS / 128;  // 782
  const int spmm_grid = (N + 3) / 4;

  auto setj = [](GJobs& g, int j, const f16* A1, int K1, const f16* A2, int K2,
                 const f16* B1, const f16* B2, const float* bias, void* C,
                 int cf16, int epi, int ldc, int bn, int c0) {
    g.A1[j] = A1; g.A2[j] = A2; g.B1[j] = B1; g.B2[j] = B2; g.bias[j] = bias; g.C[j] = C;
    g.K1[j] = K1; g.K2[j] = K2; g.cf16[j] = cf16; g.epi[j] = epi; g.ldc[j] = ldc;
    g.bn[j] = bn; g.c0[j] = c0;
  };

  // ---- layer 0 ----
  {  // G1: R1 = xh @ gcn_w0  (two 128-col blocks)
    GJobs g{};
    setj(g, 0, xh, 256, nullptr, 0, gcn_w0t, nullptr, nullptr, R1, 1, 0, 256, 128, 0);
    setj(g, 1, xh, 256, nullptr, 0, gcn_w0t, nullptr, nullptr, R1, 1, 0, 256, 128, 128);
    gemm_k<<<dim3(MB, 2), 256, 0, stream>>>(g, N);
  }
  spmm_k<4><<<spmm_grid, 256, 0, stream>>>(rpA, recA, R1, nullptr, gcn_b0, R2, 0, N);
  {  // G2: R1 = R2@pai1_0 + xh@pai2_0  |  out0 = tanh(R2@w1_w0 + b)
    GJobs g{};
    setj(g, 0, R2, 256, xh, 256, pai1_0t, pai2_0t, nullptr, R1, 1, 0, 256, 128, 0);
    setj(g, 1, R2, 256, xh, 256, pai1_0t, pai2_0t, nullptr, R1, 1, 0, 256, 128, 128);
    setj(g, 2, R2, 256, nullptr, 0, w1_w0t, nullptr, w1_b0, out, 0, 1, 64, 64, 0);
    gemm_k<<<dim3(MB, 3), 256, 0, stream>>>(g, N);
  }
  spmm_k<4><<<spmm_grid, 256, 0, stream>>>(rpL, recL, R2, R1, nullptr, R1, 1, N);
  {  // G3: T1h = R1@gcn_w1  |  out2 = tanh(R1@w2_w0 + b)
    GJobs g{};
    setj(g, 0, R1, 256, nullptr, 0, gcn_w1t, nullptr, nullptr, T1h, 1, 0, 64, 64, 0);
    setj(g, 1, R1, 256, nullptr, 0, w2_w0t, nullptr, w2_b0, out + 2 * Nd, 0, 1, 64, 64, 0);
    gemm_k<<<dim3(MB, 2), 256, 0, stream>>>(g, N);
  }

  // ---- layer 1 ----
  spmm_k<1><<<spmm_grid, 256, 0, stream>>>(rpA, recA, T1h, nullptr, gcn_b1, Ztp1h, 0, N);
  {  // G4: Z1bh = Ztp1h@pai1_1 + xh@pai2_1  |  out1 = tanh(Ztp1h@w1_w1 + b)
    GJobs g{};
    setj(g, 0, Ztp1h, 64, xh, 256, pai1_1t, pai2_1t, nullptr, Z1bh, 1, 0, 64, 64, 0);
    setj(g, 1, Ztp1h, 64, nullptr, 0, w1_w1t, nullptr, w1_b1, out + Nd, 0, 1, 64, 64, 0);
    gemm_k<<<dim3(MB, 2), 256, 0, stream>>>(g, N);
  }
  spmm_k<1><<<spmm_grid, 256, 0, stream>>>(rpL, recL, Ztp1h, Z1bh, nullptr, Z1bh, 1, N);
  {  // G5: out3 = tanh(Z1bh@w2_w1 + b)
    GJobs g{};
    setj(g, 0, Z1bh, 64, nullptr, 0, w2_w1t, nullptr, w2_b1, out + 3 * Nd, 0, 1, 64, 64, 0);
    gemm_k<<<dim3(MB, 1), 256, 0, stream>>>(g, N);
  }
}

// Round 5
// 868.083 us; speedup vs baseline: 1.8898x; 1.8898x over previous
//
#include <hip/hip_runtime.h>
#include <hip/hip_bf16.h>
#include <stdint.h>

static constexpr int N_NODES = 100000;
static constexpr int N_EDGES = 1600000;
static constexpr int PAD_ROWS = 100096;   // 782 * 128, removes GEMM A-tile bounds checks

// block-local partition CSR build: 512 rows per coarse bucket
static constexpr int CB_SHIFT = 9;
static constexpr int CRPB = 1 << CB_SHIFT;            // 512 rows / bucket
static constexpr int NCB = 196;                       // covers 100352 >= PAD_ROWS
static constexpr int CCAP = 8960;                     // mean 8192, sd 90 -> +8.5 sigma
static constexpr int CHUNK = 4096;                    // edges per partition block

typedef _Float16 f16;
using f16x8 = __attribute__((ext_vector_type(8))) _Float16;
using f16x4v = __attribute__((ext_vector_type(4))) _Float16;
using f32x4 = __attribute__((ext_vector_type(4))) float;

__device__ __forceinline__ void gld_lds16(const void* g, void* l) {
  __builtin_amdgcn_global_load_lds((const __attribute__((address_space(1))) void*)g,
                                   (__attribute__((address_space(3))) void*)l, 16, 0, 0);
}

// piecewise multi-term ReLU activation: 1.8*soft(0.1) - 0.8*soft(0.5)
__device__ __forceinline__ float custom_act(float x) {
  float s1 = fmaxf(x - 0.1f, 0.f) - fmaxf(-x - 0.1f, 0.f);
  float s2 = fmaxf(x - 0.5f, 0.f) - fmaxf(-x - 0.5f, 0.f);
  return 1.8f * s1 - 0.8f * s2;
}

// ---------------- conversions ----------------
__global__ __launch_bounds__(256) void xconv_k(const float* __restrict__ src, f16* __restrict__ dst, int n4) {
  int i = blockIdx.x * 256 + threadIdx.x;
  if (i < n4) {
    float4 v = ((const float4*)src)[i];
    f16x4v h = {(f16)v.x, (f16)v.y, (f16)v.z, (f16)v.w};
    ((f16x4v*)dst)[i] = h;
  }
}

// all 10 weight transposes (fp32 [K][N] -> f16 [N][K]) in one dispatch
struct WC {
  const float* src[10];
  f16* dst[10];
  int K[10], N[10], beg[11];
};
__global__ __launch_bounds__(256) void wconv_k(WC wc) {
  int i = blockIdx.x * 256 + threadIdx.x;
  if (i >= wc.beg[10]) return;
  int s = 0;
  while (s < 9 && i >= wc.beg[s + 1]) ++s;
  int local = i - wc.beg[s];
  int N = wc.N[s];
  int k = local / N, n = local - k * N;
  wc.dst[s][n * wc.K[s] + k] = (f16)wc.src[s][local];
}

// ---------------- block-local partition (phase 1) ----------------
__global__ __launch_bounds__(256) void part_k(const int* __restrict__ Ai, const float* __restrict__ Av,
                                              int* __restrict__ bcA, int2* __restrict__ bufA,
                                              const int* __restrict__ Li, const float* __restrict__ Lv,
                                              int* __restrict__ bcL, int2* __restrict__ bufL, int E) {
  __shared__ int histA[NCB], histL[NCB];
  __shared__ int baseA[NCB], baseL[NCB];
  int tid = threadIdx.x;
  int e0 = blockIdx.x * CHUNK;
  int e1 = min(e0 + CHUNK, E);
  for (int i = tid; i < NCB; i += 256) { histA[i] = 0; histL[i] = 0; }
  __syncthreads();
  for (int e = e0 + tid; e < e1; e += 256) {
    atomicAdd(&histA[Ai[e] >> CB_SHIFT], 1);
    atomicAdd(&histL[Li[e] >> CB_SHIFT], 1);
  }
  __syncthreads();
  if (tid < NCB) {
    int hA = histA[tid], hL = histL[tid];
    baseA[tid] = hA ? atomicAdd(&bcA[tid * 16], hA) : 0;
    baseL[tid] = hL ? atomicAdd(&bcL[tid * 16], hL) : 0;
    histA[tid] = 0;
    histL[tid] = 0;
  }
  __syncthreads();
  for (int e = e0 + tid; e < e1; e += 256) {
    {
      int r = Ai[e], c = Ai[E + e];
      int b = r >> CB_SHIFT;
      int p = baseA[b] + atomicAdd(&histA[b], 1);
      if (p < CCAP) bufA[(size_t)b * CCAP + p] = make_int2(((r & (CRPB - 1)) << 17) | c, __float_as_int(Av[e]));
    }
    {
      int r = Li[e], c = Li[E + e];
      int b = r >> CB_SHIFT;
      int p = baseL[b] + atomicAdd(&histL[b], 1);
      if (p < CCAP) bufL[(size_t)b * CCAP + p] = make_int2(((r & (CRPB - 1)) << 17) | c, __float_as_int(Lv[e]));
    }
  }
}

// scan bucket totals (strided counters) -> bucket base offsets
__global__ __launch_bounds__(1024) void scan_k(const int* __restrict__ cntA, int* __restrict__ rpA,
                                               const int* __restrict__ cntL, int* __restrict__ rpL,
                                               int n, int stride) {
  const int* cnt = blockIdx.x ? cntL : cntA;
  int* rp = blockIdx.x ? rpL : rpA;
  __shared__ int wsum[16];
  __shared__ int carry_s;
  int tid = threadIdx.x, lane = tid & 63, wv = tid >> 6;
  if (tid == 0) carry_s = 0;
  __syncthreads();
  for (int base = 0; base < n; base += 1024) {
    int i = base + tid;
    int v = (i < n) ? cnt[i * stride] : 0;
    int s = v;
    #pragma unroll
    for (int off = 1; off < 64; off <<= 1) {
      int t = __shfl_up(s, off, 64);
      if (lane >= off) s += t;
    }
    if (lane == 63) wsum[wv] = s;
    __syncthreads();
    if (wv == 0 && lane < 16) {
      int w = wsum[lane];
      #pragma unroll
      for (int off = 1; off < 16; off <<= 1) {
        int t = __shfl_up(w, off, 64);
        if (lane >= off) w += t;
      }
      wsum[lane] = w;
    }
    __syncthreads();
    int carry = carry_s;
    int woff = wv ? wsum[wv - 1] : 0;
    if (i < n) rp[i] = carry + woff + s - v;
    __syncthreads();
    if (tid == 1023) carry_s = carry + woff + s;
    __syncthreads();
  }
  if (tid == 0) rp[n] = carry_s;
}

// ---------------- per-bucket ordering (phase 2) ----------------
__global__ __launch_bounds__(256) void place_k(const int* __restrict__ bcA, const int* __restrict__ bbA,
                                               const int2* __restrict__ bufA, int* __restrict__ rpA,
                                               int2* __restrict__ recA,
                                               const int* __restrict__ bcL, const int* __restrict__ bbL,
                                               const int2* __restrict__ bufL, int* __restrict__ rpL,
                                               int2* __restrict__ recL) {
  const int b = blockIdx.x;
  const int* bc; const int* bb; const int2* buf; int* rp; int2* rec;
  if (blockIdx.y) { bc = bcL; bb = bbL; buf = bufL; rp = rpL; rec = recL; }
  else            { bc = bcA; bb = bbA; buf = bufA; rp = rpA; rec = recA; }
  __shared__ int lcnt[CRPB];
  __shared__ int wsum[4];
  int tid = threadIdx.x, lane = tid & 63, wv = tid >> 6;
  int nrec = min(bc[b * 16], CCAP);
  const int2* src = buf + (size_t)b * CCAP;
  lcnt[2 * tid] = 0;
  lcnt[2 * tid + 1] = 0;
  __syncthreads();
  for (int i = tid; i < nrec; i += 256) atomicAdd(&lcnt[src[i].x >> 17], 1);
  __syncthreads();
  int c0 = lcnt[2 * tid], c1 = lcnt[2 * tid + 1];
  int s = c0 + c1;
  int incl = s;
  #pragma unroll
  for (int off = 1; off < 64; off <<= 1) {
    int t = __shfl_up(incl, off, 64);
    if (lane >= off) incl += t;
  }
  if (lane == 63) wsum[wv] = incl;
  __syncthreads();
  int woff = 0;
  for (int w = 0; w < wv; ++w) woff += wsum[w];
  int base0 = bb[b] + woff + incl - s;    // exclusive prefix + global bucket base
  int base1 = base0 + c0;
  __syncthreads();
  lcnt[2 * tid] = base0;
  lcnt[2 * tid + 1] = base1;
  rp[b * CRPB + 2 * tid] = base0;
  rp[b * CRPB + 2 * tid + 1] = base1;
  __syncthreads();
  for (int i = tid; i < nrec; i += 256) {
    int2 r = src[i];
    int pos = atomicAdd(&lcnt[r.x >> 17], 1);
    rec[pos] = make_int2(r.x & 0x1FFFF, r.y);
  }
}

// ---------------- gather SpMM (unchanged from round 3) ----------------
template<int VEC>
__global__ __launch_bounds__(256) void spmm_k(const int* __restrict__ rp, const int2* __restrict__ rec,
                                              const f16* __restrict__ X,
                                              const f16* __restrict__ base, const float* __restrict__ bias,
                                              f16* __restrict__ out, int mode, int nrows) {
  int lane = threadIdx.x & 63;
  int row = blockIdx.x * 4 + (threadIdx.x >> 6);
  if (row >= nrows) return;
  const int M = VEC * 64;
  int p0 = __builtin_amdgcn_readfirstlane(rp[row]);
  int p1 = __builtin_amdgcn_readfirstlane(rp[row + 1]);
  float acc[VEC] = {};
  int p = p0;
  for (; p + 7 < p1; p += 8) {
    int2 e[8];
    #pragma unroll
    for (int u = 0; u < 8; ++u) e[u] = rec[p + u];
    if (VEC == 4) {
      f16x4v xv[8];
      #pragma unroll
      for (int u = 0; u < 8; ++u) xv[u] = *(const f16x4v*)(X + (size_t)e[u].x * M + lane * 4);
      #pragma unroll
      for (int u = 0; u < 8; ++u) {
        float v = __int_as_float(e[u].y);
        #pragma unroll
        for (int j = 0; j < 4; ++j) acc[j] += v * (float)xv[u][j];
      }
    } else {
      float xv[8];
      #pragma unroll
      for (int u = 0; u < 8; ++u) xv[u] = (float)X[(size_t)e[u].x * M + lane];
      #pragma unroll
      for (int u = 0; u < 8; ++u) acc[0] += __int_as_float(e[u].y) * xv[u];
    }
  }
  for (; p + 1 < p1; p += 2) {
    int2 e0 = rec[p], e1 = rec[p + 1];
    float v0 = __int_as_float(e0.y), v1 = __int_as_float(e1.y);
    if (VEC == 4) {
      f16x4v x0 = *(const f16x4v*)(X + (size_t)e0.x * M + lane * 4);
      f16x4v x1 = *(const f16x4v*)(X + (size_t)e1.x * M + lane * 4);
      #pragma unroll
      for (int j = 0; j < 4; ++j) acc[j] += v0 * (float)x0[j] + v1 * (float)x1[j];
    } else {
      float x0 = (float)X[(size_t)e0.x * M + lane];
      float x1 = (float)X[(size_t)e1.x * M + lane];
      acc[0] += v0 * x0 + v1 * x1;
    }
  }
  if (p < p1) {
    int2 e0 = rec[p];
    float v0 = __int_as_float(e0.y);
    if (VEC == 4) {
      f16x4v x0 = *(const f16x4v*)(X + (size_t)e0.x * M + lane * 4);
      #pragma unroll
      for (int j = 0; j < 4; ++j) acc[j] += v0 * (float)x0[j];
    } else {
      acc[0] += v0 * (float)X[(size_t)e0.x * M + lane];
    }
  }
  size_t o = (size_t)row * M + (size_t)lane * VEC;
  if (VEC == 4) {
    f16x4v r;
    if (mode == 0) {
      #pragma unroll
      for (int j = 0; j < 4; ++j) r[j] = (f16)fmaxf(acc[j] + bias[lane * 4 + j], 0.f);
    } else {
      f16x4v bv = *(const f16x4v*)(base + o);
      #pragma unroll
      for (int j = 0; j < 4; ++j) r[j] = (f16)custom_act((float)bv[j] - acc[j]);
    }
    *(f16x4v*)(out + o) = r;
  } else {
    if (mode == 0) out[o] = (f16)fmaxf(acc[0] + bias[lane], 0.f);
    else out[o] = (f16)custom_act((float)base[o] - acc[0]);
  }
}

// ---------------- multi-job f16 MFMA GEMM, BK=64, XOR-swizzled LDS ----------------
// template<BN>: all acc indexing compile-time (rule #20 — runtime-indexed vector
// arrays spill to scratch; round-4 regression). Jobs in one dispatch share BN.
// LDS layout: row stride 64 f16; 16B granule g of row r stored at slot g^(r&7)
// (applied by pre-swizzling the per-lane GLOBAL source; gld_lds dest stays linear).
struct GJobs {
  const f16* A1[3]; const f16* A2[3];
  const f16* B1[3]; const f16* B2[3];
  const float* bias[3];
  void* C[3];
  int K1[3], K2[3], cf16[3], epi[3], ldc[3], c0[3];
};

template<int BN>
__global__ __launch_bounds__(256) void gemm_k(GJobs jb, int nrows) {
  constexpr int NBT = BN / 16;
  constexpr int BROWS = (BN == 128) ? 32 : 16;
  __shared__ f16 As[128 * 64];
  __shared__ f16 Bs[BN * 64];
  const int j = blockIdx.y;
  const int c0 = jb.c0[j], ldc = jb.ldc[j];
  int tid = threadIdx.x, lane = tid & 63, wv = tid >> 6;
  int m16 = lane & 15, quad = lane >> 4;
  int r0 = blockIdx.x * 128;
  int wr0 = wv * 32;
  f32x4 acc[2][NBT] = {};
  // staging: lane l -> row (l>>3), granule slot (l&7); global granule = slot ^ (row&7)
  int srow = lane >> 3;
  int sg = (lane & 7) ^ (srow & 7);
  int aswz = (m16 & 7) * 8;   // f16 offset of XOR term for fragment reads
  for (int src = 0; src < 2; ++src) {
    const f16* A = src ? jb.A2[j] : jb.A1[j];
    if (!A) continue;
    int K = src ? jb.K2[j] : jb.K1[j];
    const f16* Bt = src ? jb.B2[j] : jb.B1[j];
    const f16* gA = A + (size_t)(r0 + wr0 + srow) * K + sg * 8;
    const f16* gB = Bt + (size_t)(c0 + wv * BROWS + srow) * K + sg * 8;
    f16* lA = &As[wr0 * 64];
    f16* lB = &Bs[wv * BROWS * 64];
    for (int k0 = 0; k0 < K; k0 += 64) {
      #pragma unroll
      for (int c = 0; c < 4; ++c) gld_lds16(gA + k0 + (size_t)(c * 8) * K, lA + c * 512);
      gld_lds16(gB + k0, lB);
      gld_lds16(gB + k0 + (size_t)8 * K, lB + 512);
      if (BN == 128) {
        gld_lds16(gB + k0 + (size_t)16 * K, lB + 1024);
        gld_lds16(gB + k0 + (size_t)24 * K, lB + 1536);
      }
      __syncthreads();
      #pragma unroll
      for (int ks = 0; ks < 2; ++ks) {
        int gsl = ((ks * 4 + quad) * 8) ^ aswz;
        f16x8 a0 = *(const f16x8*)&As[(wr0 + m16) * 64 + gsl];
        f16x8 a1 = *(const f16x8*)&As[(wr0 + 16 + m16) * 64 + gsl];
        #pragma unroll
        for (int bt = 0; bt < NBT; ++bt) {
          f16x8 b = *(const f16x8*)&Bs[(bt * 16 + m16) * 64 + gsl];
          acc[0][bt] = __builtin_amdgcn_mfma_f32_16x16x32_f16(a0, b, acc[0][bt], 0, 0, 0);
          acc[1][bt] = __builtin_amdgcn_mfma_f32_16x16x32_f16(a1, b, acc[1][bt], 0, 0, 0);
        }
      }
      __syncthreads();
    }
  }
  const float* bias = jb.bias[j];
  int cf16 = jb.cf16[j], epi = jb.epi[j];
  void* C = jb.C[j];
  #pragma unroll
  for (int rt = 0; rt < 2; ++rt) {
    #pragma unroll
    for (int bt = 0; bt < NBT; ++bt) {
      #pragma unroll
      for (int jj = 0; jj < 4; ++jj) {
        int row = r0 + wr0 + rt * 16 + quad * 4 + jj;
        if (row >= nrows) continue;
        int colp = c0 + bt * 16 + m16;
        float v = acc[rt][bt][jj];
        if (bias) v += bias[colp];
        if (epi == 1) v = tanhf(v);
        size_t o = (size_t)row * ldc + colp;
        if (cf16) ((f16*)C)[o] = (f16)v;
        else ((float*)C)[o] = v;
      }
    }
  }
}

extern "C" void kernel_launch(void* const* d_in, const int* in_sizes, int n_in,
                              void* d_out, int out_size, void* d_ws, size_t ws_size,
                              hipStream_t stream) {
  const float* x  = (const float*)d_in[0];
  const int*   Ai = (const int*)d_in[1];
  const float* Av = (const float*)d_in[2];
  const int*   Li = (const int*)d_in[3];
  const float* Lv = (const float*)d_in[4];
  const float* gcn_w0 = (const float*)d_in[5];
  const float* gcn_b0 = (const float*)d_in[6];
  const float* pai1_0 = (const float*)d_in[7];
  const float* pai2_0 = (const float*)d_in[8];
  const float* w1_w0  = (const float*)d_in[9];
  const float* w1_b0  = (const float*)d_in[10];
  const float* w2_w0  = (const float*)d_in[11];
  const float* w2_b0  = (const float*)d_in[12];
  const float* gcn_w1 = (const float*)d_in[13];
  const float* gcn_b1 = (const float*)d_in[14];
  const float* pai1_1 = (const float*)d_in[15];
  const float* pai2_1 = (const float*)d_in[16];
  const float* w1_w1  = (const float*)d_in[17];
  const float* w1_b1  = (const float*)d_in[18];
  const float* w2_w1  = (const float*)d_in[19];
  const float* w2_b1  = (const float*)d_in[20];
  float* out = (float*)d_out;

  const int N = N_NODES, E = N_EDGES;
  const size_t PH = (size_t)PAD_ROWS * 256;
  const size_t Pd = (size_t)PAD_ROWS * 64;
  const size_t Nd = (size_t)N * 64;

  // ---- workspace carve ----
  f16* xh  = (f16*)d_ws;               // PH
  f16* R1  = xh + PH;                  // PH
  f16* R2  = R1 + PH;                  // PH
  f16* wts = R2 + PH;                  // 274432 f16 weight pool
  f16* gcn_w0t = wts;
  f16* pai1_0t = gcn_w0t + 65536;
  f16* pai2_0t = pai1_0t + 65536;
  f16* w1_w0t  = pai2_0t + 65536;
  f16* w2_w0t  = w1_w0t + 16384;
  f16* gcn_w1t = w2_w0t + 16384;
  f16* pai2_1t = gcn_w1t + 16384;
  f16* pai1_1t = pai2_1t + 16384;
  f16* w1_w1t  = pai1_1t + 4096;
  f16* w2_w1t  = w1_w1t + 4096;
  int2* recA = (int2*)(((uintptr_t)(w2_w1t + 4096) + 255) & ~(uintptr_t)255);  // E
  int2* recL = recA + E;                                                        // E
  int*  rpA  = (int*)(recL + E);       // PAD_ROWS + 512
  int*  rpL  = rpA + (PAD_ROWS + 512);
  int*  bcA  = rpL + (PAD_ROWS + 512); // NCB*16
  int*  bcL  = bcA + NCB * 16;
  int*  bbA  = bcL + NCB * 16;         // NCB+1
  int*  bbL  = bbA + (NCB + 1);        // NCB+1

  int2* bufA = (int2*)R1;                       // aliases R1 (stream-ordered)
  int2* bufL = bufA + (size_t)NCB * CCAP;

  // layer-1 sub-buffers inside R2 (ldc=64, padded rows)
  f16* T1h   = R2;
  f16* Ztp1h = R2 + Pd;
  f16* Z1bh  = R2 + 2 * Pd;

  // ---- conversions ----
  xconv_k<<<(int)(((size_t)N * 64 + 255) / 256), 256, 0, stream>>>(x, xh, N * 64);
  {
    WC wc;
    const float* s[10] = {gcn_w0, pai1_0, pai2_0, w1_w0, w2_w0, gcn_w1, pai2_1, pai1_1, w1_w1, w2_w1};
    f16* d[10] = {gcn_w0t, pai1_0t, pai2_0t, w1_w0t, w2_w0t, gcn_w1t, pai2_1t, pai1_1t, w1_w1t, w2_w1t};
    int K[10] = {256, 256, 256, 256, 256, 256, 256, 64, 64, 64};
    int Nn[10] = {256, 256, 256, 64, 64, 64, 64, 64, 64, 64};
    int off = 0;
    for (int i = 0; i < 10; ++i) {
      wc.src[i] = s[i]; wc.dst[i] = d[i]; wc.K[i] = K[i]; wc.N[i] = Nn[i];
      wc.beg[i] = off; off += K[i] * Nn[i];
    }
    wc.beg[10] = off;
    wconv_k<<<(off + 255) / 256, 256, 0, stream>>>(wc);
  }

  // ---- CSR build ----
  hipMemsetAsync(bcA, 0, sizeof(int) * (size_t)NCB * 16 * 2, stream);
  part_k<<<(E + CHUNK - 1) / CHUNK, 256, 0, stream>>>(Ai, Av, bcA, bufA, Li, Lv, bcL, bufL, E);
  scan_k<<<2, 1024, 0, stream>>>(bcA, bbA, bcL, bbL, NCB, 16);
  place_k<<<dim3(NCB, 2), 256, 0, stream>>>(bcA, bbA, bufA, rpA, recA,
                                            bcL, bbL, bufL, rpL, recL);

  const int MB = PAD_ROWS / 128;  // 782
  const int spmm_grid = (N + 3) / 4;

  auto setj = [](GJobs& g, int j, const f16* A1, int K1, const f16* A2, int K2,
                 const f16* B1, const f16* B2, const float* bias, void* C,
                 int cf16, int epi, int ldc, int c0) {
    g.A1[j] = A1; g.A2[j] = A2; g.B1[j] = B1; g.B2[j] = B2; g.bias[j] = bias; g.C[j] = C;
    g.K1[j] = K1; g.K2[j] = K2; g.cf16[j] = cf16; g.epi[j] = epi; g.ldc[j] = ldc;
    g.c0[j] = c0;
  };

  // ---- layer 0 ----
  {  // G1: R1 = xh @ gcn_w0  (two 128-col blocks)
    GJobs g{};
    setj(g, 0, xh, 256, nullptr, 0, gcn_w0t, nullptr, nullptr, R1, 1, 0, 256, 0);
    setj(g, 1, xh, 256, nullptr, 0, gcn_w0t, nullptr, nullptr, R1, 1, 0, 256, 128);
    gemm_k<128><<<dim3(MB, 2), 256, 0, stream>>>(g, N);
  }
  spmm_k<4><<<spmm_grid, 256, 0, stream>>>(rpA, recA, R1, nullptr, gcn_b0, R2, 0, N);
  {  // G2a: R1 = R2@pai1_0 + xh@pai2_0  (two 128-col blocks)
    GJobs g{};
    setj(g, 0, R2, 256, xh, 256, pai1_0t, pai2_0t, nullptr, R1, 1, 0, 256, 0);
    setj(g, 1, R2, 256, xh, 256, pai1_0t, pai2_0t, nullptr, R1, 1, 0, 256, 128);
    gemm_k<128><<<dim3(MB, 2), 256, 0, stream>>>(g, N);
  }
  {  // G2b: out0 = tanh(R2@w1_w0 + b)
    GJobs g{};
    setj(g, 0, R2, 256, nullptr, 0, w1_w0t, nullptr, w1_b0, out, 0, 1, 64, 0);
    gemm_k<64><<<dim3(MB, 1), 256, 0, stream>>>(g, N);
  }
  spmm_k<4><<<spmm_grid, 256, 0, stream>>>(rpL, recL, R2, R1, nullptr, R1, 1, N);
  {  // G3: T1h = R1@gcn_w1  |  out2 = tanh(R1@w2_w0 + b)
    GJobs g{};
    setj(g, 0, R1, 256, nullptr, 0, gcn_w1t, nullptr, nullptr, T1h, 1, 0, 64, 0);
    setj(g, 1, R1, 256, nullptr, 0, w2_w0t, nullptr, w2_b0, out + 2 * Nd, 0, 1, 64, 0);
    gemm_k<64><<<dim3(MB, 2), 256, 0, stream>>>(g, N);
  }

  // ---- layer 1 ----
  spmm_k<1><<<spmm_grid, 256, 0, stream>>>(rpA, recA, T1h, nullptr, gcn_b1, Ztp1h, 0, N);
  {  // G4: Z1bh = Ztp1h@pai1_1 + xh@pai2_1  |  out1 = tanh(Ztp1h@w1_w1 + b)
    GJobs g{};
    setj(g, 0, Ztp1h, 64, xh, 256, pai1_1t, pai2_1t, nullptr, Z1bh, 1, 0, 64, 0);
    setj(g, 1, Ztp1h, 64, nullptr, 0, w1_w1t, nullptr, w1_b1, out + Nd, 0, 1, 64, 0);
    gemm_k<64><<<dim3(MB, 2), 256, 0, stream>>>(g, N);
  }
  spmm_k<1><<<spmm_grid, 256, 0, stream>>>(rpL, recL, Ztp1h, Z1bh, nullptr, Z1bh, 1, N);
  {  // G5: out3 = tanh(Z1bh@w2_w1 + b)
    GJobs g{};
    setj(g, 0, Z1bh, 64, nullptr, 0, w2_w1t, nullptr, w2_b1, out + 3 * Nd, 0, 1, 64, 0);
    gemm_k<64><<<dim3(MB, 1), 256, 0, stream>>>(g, N);
  }
}